// Round 1
// 718.020 us; speedup vs baseline: 1.0041x; 1.0041x over previous
//
#include <hip/hip_runtime.h>
#include <stdint.h>

#define NB   4096   // batch rows
#define LDIM 4096   // latent dim
#define KK   10     // k
#define TPB  256
#define CAP  1024   // survivor buffer entries (u64) -> 8 KB LDS

__device__ __forceinline__ unsigned long long wave_min_u64(unsigned long long v) {
#pragma unroll
    for (int off = 1; off < 64; off <<= 1) {
        const unsigned long long o = __shfl_xor(v, off, 64);
        if (o < v) v = o;
    }
    return v;
}

__global__ __launch_bounds__(TPB) void topk_sparsemax(
    const float* __restrict__ logits,
    float* __restrict__ bv,      // [NB, KK, LDIM]
    float* __restrict__ distr,   // [NB, KK]
    float* __restrict__ ent)     // [1]
{
    __shared__ float s_wsum[4];
    __shared__ int   s_pos[KK];     // indices of k smallest |logit| (cost-ascending)
    __shared__ int   s_sign[KK];    // base bit at those positions (logit > 0)
    __shared__ int   s_bestm[KK];   // chosen flip-subset masks (cost ascending)
    __shared__ int   s_cnt;
    __shared__ unsigned long long s_cand[CAP];

    const int b    = blockIdx.x;
    const int t    = threadIdx.x;
    const int lane = t & 63;
    const int wv   = t >> 6;
    const float* __restrict__ row = logits + (size_t)b * LDIM;

    // ---- load 16 logits/thread, coalesced: element i -> col ((i>>2)<<10) + 4t + (i&3)
    float vals[16];
#pragma unroll
    for (int q = 0; q < 4; q++) {
        const float4 f = *(const float4*)(row + (q << 10) + (t << 2));
        vals[q*4+0] = f.x; vals[q*4+1] = f.y; vals[q*4+2] = f.z; vals[q*4+3] = f.w;
    }

    // ---- S0 = sum of positive logits (identical order to previous passing kernel)
    float s0 = 0.f;
#pragma unroll
    for (int i = 0; i < 16; i++) s0 += vals[i] > 0.f ? vals[i] : 0.f;
#pragma unroll
    for (int off = 1; off < 64; off <<= 1) s0 += __shfl_xor(s0, off, 64);
    if (lane == 0) s_wsum[wv] = s0;
    // (visibility of s_wsum guaranteed by the compaction barriers below)

    // ---- threshold compaction: survivors |v| < T into LDS.
    // Exact: if cnt >= KK, the KK smallest (cost,idx)-packed keys are all < T,
    // hence all present in s_cand. Retry loop adjusts T; fallback below is exact.
    float T = 0.02f;   // ~65 expected survivors for N(0,1) x 4096
    int cnt = 0;
    for (int attempt = 0; attempt < 15; attempt++) {
        if (t == 0) s_cnt = 0;
        __syncthreads();
#pragma unroll
        for (int i = 0; i < 16; i++) {
            const float v    = vals[i];
            const float cost = fabsf(v);
            if (cost < T) {
                const int idx = ((i >> 2) << 10) + (t << 2) + (i & 3);
                const unsigned long long pk =
                    ((unsigned long long)__float_as_uint(cost) << 32)
                    | (unsigned)((idx << 1) | (v > 0.f ? 1 : 0));
                const int p = atomicAdd(&s_cnt, 1);
                if (p < CAP) s_cand[p] = pk;
            }
        }
        __syncthreads();
        cnt = s_cnt;                      // uniform across block
        if (cnt >= KK && cnt <= CAP) break;
        T = (cnt < KK) ? T * 4.0f : T * 0.25f;
        __syncthreads();                  // protect s_cnt reset on retry
    }

    // ---- bulk bv write FIRST: 640 MB stream issued before wave0's selection,
    // so the HBM store drain overlaps the selection compute. No barrier until fixup.
    float4 base4[4];
#pragma unroll
    for (int q = 0; q < 4; q++) {
        base4[q].x = vals[q*4+0] > 0.f ? 1.f : 0.f;
        base4[q].y = vals[q*4+1] > 0.f ? 1.f : 0.f;
        base4[q].z = vals[q*4+2] > 0.f ? 1.f : 0.f;
        base4[q].w = vals[q*4+3] > 0.f ? 1.f : 0.f;
    }
    float* out0 = bv + (size_t)b * (KK * LDIM);
#pragma unroll
    for (int c = 0; c < KK; c++) {
        float* orow = out0 + c * LDIM + (t << 2);
#pragma unroll
        for (int q = 0; q < 4; q++)
            *(float4*)(orow + (q << 10)) = base4[q];
    }

    // ---- wave 0 only: stage-1 select, subset sums, stage-2 select, sparsemax.
    // Selection uses strictly-increasing packed keys (all pk unique via idx/m bits),
    // so "pk > prev" replaces taken-masks. No block barriers in here.
    if (wv == 0) {
        const float S0 = (s_wsum[0] + s_wsum[1]) + (s_wsum[2] + s_wsum[3]);
        float csm[KK];
        unsigned long long prev = 0ull;

        if (cnt >= KK && cnt <= CAP) {
            const int nc = cnt;
#pragma unroll
            for (int c = 0; c < KK; c++) {
                unsigned long long best = ~0ull;
                for (int p = lane; p < nc; p += 64) {
                    const unsigned long long pk = s_cand[p];
                    if ((c == 0 || pk > prev) && pk < best) best = pk;
                }
                best = wave_min_u64(best);
                prev = best;
                csm[c] = __uint_as_float((unsigned)(best >> 32));
                if (lane == 0) {
                    const unsigned lo = (unsigned)best;
                    s_pos[c]  = (int)(lo >> 1);
                    s_sign[c] = (int)(lo & 1u);
                }
            }
        } else {
            // exact fallback (pathological data only): wave0 rescans full row from L2
#pragma unroll
            for (int c = 0; c < KK; c++) {
                unsigned long long best = ~0ull;
                for (int p = lane; p < LDIM; p += 64) {
                    const float v    = row[p];
                    const float cost = fabsf(v);
                    const unsigned long long pk =
                        ((unsigned long long)__float_as_uint(cost) << 32)
                        | (unsigned)((p << 1) | (v > 0.f ? 1 : 0));
                    if ((c == 0 || pk > prev) && pk < best) best = pk;
                }
                best = wave_min_u64(best);
                prev = best;
                csm[c] = __uint_as_float((unsigned)(best >> 32));
                if (lane == 0) {
                    const unsigned lo = (unsigned)best;
                    s_pos[c]  = (int)(lo >> 1);
                    s_sign[c] = (int)(lo & 1u);
                }
            }
        }

        // stage 2: 1024 subset sums, m = (lane<<4)|i, ascending-j accumulation
        // (identical FP order to the passing kernel's einsum replication)
        float sums[16];
#pragma unroll
        for (int i = 0; i < 16; i++) {
            const int m = (lane << 4) | i;
            float acc = 0.f;
#pragma unroll
            for (int j = 0; j < KK; j++) acc += (m & (1 << j)) ? csm[j] : 0.f;
            sums[i] = acc;
        }

        float zc[KK];
        unsigned long long prev2 = 0ull;
#pragma unroll
        for (int c = 0; c < KK; c++) {
            unsigned long long best = ~0ull;
#pragma unroll
            for (int i = 0; i < 16; i++) {
                const unsigned long long pk =
                    ((unsigned long long)__float_as_uint(sums[i]) << 32)
                    | (unsigned)((lane << 4) | i);
                if ((c == 0 || pk > prev2) && pk < best) best = pk;
            }
            best = wave_min_u64(best);
            prev2 = best;
            zc[c] = S0 - __uint_as_float((unsigned)(best >> 32));
            if (lane == 0) s_bestm[c] = (int)((unsigned)best & 1023u);
        }

        // sparsemax + entropy (identical arithmetic to passing kernel)
        if (lane == 0) {
            float acc = 0.f; int ks = 0;
#pragma unroll
            for (int r = 1; r <= KK; r++) {
                acc += zc[r-1];
                if (1.f + (float)r * zc[r-1] > acc) ks++;
            }
            float acc2 = 0.f;
#pragma unroll
            for (int r = 0; r < KK; r++) if (r < ks) acc2 += zc[r];
            const float tau = (acc2 - 1.f) / (float)ks;
            float entl = 0.f;
            float* drow = distr + b * KK;
#pragma unroll
            for (int c = 0; c < KK; c++) {
                float p = zc[c] - tau;
                p = p > 0.f ? p : 0.f;
                drow[c] = p;
                if (p > 0.f) entl -= p * logf(p);
            }
            atomicAdd(ent, entl * (1.0f / (float)NB));
        }
    }

    // ---- single barrier: drains bulk stores (vmcnt0) + publishes s_pos/s_sign/s_bestm
    __syncthreads();
    if (t < KK * KK) {
        const int c = t / KK, j = t % KK;
        if ((s_bestm[c] >> j) & 1)
            out0[c * LDIM + s_pos[j]] = s_sign[j] ? 0.f : 1.f;
    }
}

extern "C" void kernel_launch(void* const* d_in, const int* in_sizes, int n_in,
                              void* d_out, int out_size, void* d_ws, size_t ws_size,
                              hipStream_t stream)
{
    const float* logits = (const float*)d_in[0];
    float* out   = (float*)d_out;
    float* bv    = out;
    float* distr = out + (size_t)NB * KK * LDIM;
    float* ent   = distr + (size_t)NB * KK;
    // harness poisons d_out with 0xAA before timed replays; entropy is accumulated
    hipMemsetAsync(ent, 0, sizeof(float), stream);
    topk_sparsemax<<<dim3(NB), dim3(TPB), 0, stream>>>(logits, bv, distr, ent);
}